// Round 1
// baseline (37.227 us; speedup 1.0000x reference)
//
#include <hip/hip_runtime.h>

#define N_ELEMS  65536
#define NTHREADS 1024
#define EPT      (N_ELEMS / NTHREADS)   // 64 elements per thread

// Reverse affine scan: v_t = a_t * v_{t+1} + b_t, with a_t = gamma*l_t,
// b_t = gamma - a_t.  Composition (A1,B1) o (A2,B2) = (A1*A2, A1*B2 + B1),
// where (A,B) means f(v) = A*v + B and "o" is "apply second, then first"
// (left factor is the earlier-index / outer function).
__global__ __launch_bounds__(NTHREADS) void learnable_td_kernel(
        const float* __restrict__ raw_gamma,
        const float* __restrict__ raw_lambd,
        float* __restrict__ out) {
    const int tid  = threadIdx.x;
    const int base = tid * EPT;

    const float gamma = fmaxf(tanhf(raw_gamma[0]), 0.0f);

    // ---- Phase A: load lambda chunk, a[k] = gamma * max(tanh(raw),0) ----
    float a[EPT];
#pragma unroll
    for (int k = 0; k < EPT; k += 4) {
        const float4 r = *reinterpret_cast<const float4*>(raw_lambd + base + k);
        a[k + 0] = gamma * fmaxf(tanhf(r.x), 0.0f);
        a[k + 1] = gamma * fmaxf(tanhf(r.y), 0.0f);
        a[k + 2] = gamma * fmaxf(tanhf(r.z), 0.0f);
        a[k + 3] = gamma * fmaxf(tanhf(r.w), 0.0f);
    }

    // ---- per-thread chunk composition F_i = f_base o ... o f_{base+63} ----
    float A = 1.0f, B = 0.0f;
#pragma unroll
    for (int k = EPT - 1; k >= 0; --k) {
        const float ak = a[k];
        B = fmaf(ak, B, gamma - ak);   // G <- f_k o G
        A *= ak;
    }

    // ---- Hillis-Steele inclusive SUFFIX scan over 1024 compositions ----
    __shared__ float sA[2][NTHREADS];
    __shared__ float sB[2][NTHREADS];
    sA[0][tid] = A;
    sB[0][tid] = B;
    __syncthreads();
    int src = 0;
#pragma unroll
    for (int d = 1; d < NTHREADS; d <<= 1) {
        float nA = sA[src][tid];
        float nB = sB[src][tid];
        if (tid + d < NTHREADS) {
            const float A2 = sA[src][tid + d];
            const float B2 = sB[src][tid + d];
            nB = fmaf(nA, B2, nB);     // cur_i o cur_{i+d}
            nA = nA * A2;
        }
        sA[src ^ 1][tid] = nA;
        sB[src ^ 1][tid] = nB;
        __syncthreads();
        src ^= 1;
    }

    // incoming v for this chunk: v_{e_i} = S_{i+1}(1) = A+B  (1.0 for last)
    const float v_in = (tid == NTHREADS - 1)
                           ? 1.0f
                           : (sA[src][tid + 1] + sB[src][tid + 1]);

    // ---- Phase B: replay chunk, write raw w, accumulate partial sum ----
    float v   = v_in;
    float sum = 0.0f;
#pragma unroll
    for (int k = EPT - 1; k >= 0; --k) {
        const float ak = a[k];
        v = fmaf(ak, v, gamma - ak);
        const float w = fmaxf(1.0f - v, 1e-8f);
        out[base + k] = w;
        sum += w;
    }

    // ---- block reduction for the mean ----
#pragma unroll
    for (int off = 32; off > 0; off >>= 1)
        sum += __shfl_down(sum, off, 64);

    __shared__ float ssum[NTHREADS / 64];
    __shared__ float sscale;
    if ((tid & 63) == 0) ssum[tid >> 6] = sum;
    __syncthreads();
    if (tid == 0) {
        float tot = 0.0f;
#pragma unroll
        for (int i = 0; i < NTHREADS / 64; ++i) tot += ssum[i];
        const float mean = tot / (float)N_ELEMS;
        sscale = 1.0f / fmaxf(mean, 1e-8f);
    }
    __syncthreads();
    const float scale = sscale;

    // ---- Phase C: coalesced in-place scale (single workgroup => all w
    // writes above are visible after the barriers) ----
#pragma unroll
    for (int i = 0; i < N_ELEMS / (NTHREADS * 4); ++i) {
        const int idx = (i * NTHREADS + tid) * 4;
        float4 w4 = *reinterpret_cast<float4*>(out + idx);
        w4.x *= scale;
        w4.y *= scale;
        w4.z *= scale;
        w4.w *= scale;
        *reinterpret_cast<float4*>(out + idx) = w4;
    }
}

extern "C" void kernel_launch(void* const* d_in, const int* in_sizes, int n_in,
                              void* d_out, int out_size, void* d_ws, size_t ws_size,
                              hipStream_t stream) {
    const float* raw_gamma = (const float*)d_in[0];
    const float* raw_lambd = (const float*)d_in[1];
    float* out = (float*)d_out;

    learnable_td_kernel<<<1, NTHREADS, 0, stream>>>(raw_gamma, raw_lambd, out);
}

// Round 2
// 14.878 us; speedup vs baseline: 2.5022x; 2.5022x over previous
//
#include <hip/hip_runtime.h>

#define N_ELEMS 65536
#define NBLK    256   // blocks in K1/K3; also elements per block
#define BTH     256   // threads per block

// Reverse affine scan: v_t = a_t * v_{t+1} + b_t with a_t = gamma*l_t,
// b_t = gamma - a_t.  (A1,B1) o (A2,B2) = (A1*A2, A1*B2 + B1) where the LEFT
// factor is the earlier-index (outer) map.

// fast tanh for x >= 0 (inputs are arctanh of values in [0,1), max ~7.25)
__device__ __forceinline__ float fast_tanh_pos(float x) {
    const float t = __expf(2.0f * x);                    // v_exp_f32 path
    return (t - 1.0f) * __builtin_amdgcn_rcpf(t + 1.0f); // ~1 ulp
}

// in-wave inclusive SUFFIX scan of affine pairs: lane l -> comp(l..63)
__device__ __forceinline__ void wave_suffix_scan(float& A, float& B, int lane) {
#pragma unroll
    for (int d = 1; d < 64; d <<= 1) {
        const float A2 = __shfl_down(A, d, 64);
        const float B2 = __shfl_down(B, d, 64);
        if (lane + d < 64) { B = fmaf(A, B2, B); A = A * A2; }
    }
}

// ---------------- K1: per-block affine composition -> ws ----------------
__global__ __launch_bounds__(BTH) void k1_blockcomp(
        const float* __restrict__ raw_gamma,
        const float* __restrict__ raw_lambd,
        float* __restrict__ wsA, float* __restrict__ wsB) {
    const int tid  = threadIdx.x;
    const int blk  = blockIdx.x;
    const int lane = tid & 63;
    const int w    = tid >> 6;

    const float gamma = fmaxf(fast_tanh_pos(raw_gamma[0]), 0.0f);
    const float lam   = fmaxf(fast_tanh_pos(raw_lambd[blk * BTH + tid]), 0.0f);
    float A = gamma * lam;
    float B = gamma - A;

    wave_suffix_scan(A, B, lane);

    __shared__ float sA[4], sB[4];
    if (lane == 0) { sA[w] = A; sB[w] = B; }
    __syncthreads();
    if (tid == 0) {
        float TA = sA[0], TB = sB[0];
#pragma unroll
        for (int j = 1; j < 4; ++j) { TB = fmaf(TA, sB[j], TB); TA *= sA[j]; }
        wsA[blk] = TA;
        wsB[blk] = TB;
    }
}

// ------- K3: incoming v per block + per-element apply + block sums -------
__global__ __launch_bounds__(BTH) void k3_compute(
        const float* __restrict__ raw_gamma,
        const float* __restrict__ raw_lambd,
        const float* __restrict__ wsA, const float* __restrict__ wsB,
        float* __restrict__ out, float* __restrict__ blocksums) {
    const int tid  = threadIdx.x;
    const int blk  = blockIdx.x;
    const int lane = tid & 63;
    const int w    = tid >> 6;

    __shared__ float sA[4], sB[4], swsum[4];
    __shared__ float sv;

    const float gamma = fmaxf(fast_tanh_pos(raw_gamma[0]), 0.0f);

    // ---- phase 0: v_blk = (comp of blocks blk+1..255)(1) ----
    {
        float A = wsA[tid], B = wsB[tid];
        wave_suffix_scan(A, B, lane);
        if (lane == 0) { sA[w] = A; sB[w] = B; }
        __syncthreads();
        float TA = A, TB = B;                 // comp(tid .. end of its wave)
        for (int j = w + 1; j < 4; ++j) { TB = fmaf(TA, sB[j], TB); TA *= sA[j]; }
        // (TA,TB) now = comp(blocks tid..255)
        __syncthreads();                      // all sA/sB reads done before reuse
        if (tid == blk + 1) sv = TA + TB;     // S_{blk+1}(1)
        if (blk == NBLK - 1 && tid == 0) sv = 1.0f;
        __syncthreads();
    }
    const float v_blk = sv;

    // ---- phase 1: own-block exclusive suffix, apply, write raw w ----
    const int g = blk * BTH + tid;
    const float lam = fmaxf(fast_tanh_pos(raw_lambd[g]), 0.0f);
    const float a   = gamma * lam;
    float A = a, B = gamma - a;

    wave_suffix_scan(A, B, lane);
    __syncthreads();                          // sv read done; sA/sB reuse below
    if (lane == 0) { sA[w] = A; sB[w] = B; }
    __syncthreads();

    float TA = 1.0f, TB = 0.0f;               // tail: waves w+1..3
    for (int j = w + 1; j < 4; ++j) { TB = fmaf(TA, sB[j], TB); TA *= sA[j]; }

    // full inclusive suffix for this lane, then shift by 1 for exclusive
    const float fA = A * TA;
    const float fB = fmaf(A, TB, B);
    float eA = __shfl_down(fA, 1, 64);
    float eB = __shfl_down(fB, 1, 64);
    if (lane == 63) { eA = TA; eB = TB; }

    const float v_in = fmaf(eA, v_blk, eB);   // v entering element g
    const float v    = fmaf(a, v_in, gamma - a);
    const float wq   = fmaxf(1.0f - v, 1e-8f);
    out[g] = wq;

    // ---- deterministic block sum ----
    float s = wq;
#pragma unroll
    for (int off = 32; off > 0; off >>= 1) s += __shfl_down(s, off, 64);
    if (lane == 0) swsum[w] = s;
    __syncthreads();
    if (tid == 0)
        blocksums[blk] = (swsum[0] + swsum[1]) + (swsum[2] + swsum[3]);
}

// ---------------- K4: global mean + in-place scale ----------------
__global__ __launch_bounds__(BTH) void k4_scale(
        const float* __restrict__ blocksums, float* __restrict__ out) {
    const int tid  = threadIdx.x;
    const int lane = tid & 63;

    __shared__ float s4[4];
    __shared__ float sscale;

    float s = blocksums[tid];                 // 256 sums, 256 threads
#pragma unroll
    for (int off = 32; off > 0; off >>= 1) s += __shfl_down(s, off, 64);
    if (lane == 0) s4[tid >> 6] = s;
    __syncthreads();
    if (tid == 0) {
        const float tot  = (s4[0] + s4[1]) + (s4[2] + s4[3]);
        const float mean = tot * (1.0f / (float)N_ELEMS);
        sscale = 1.0f / fmaxf(mean, 1e-8f);
    }
    __syncthreads();
    const float scale = sscale;

    const int idx = (blockIdx.x * BTH + tid) * 4;
    float4 w4 = *reinterpret_cast<float4*>(out + idx);
    w4.x *= scale; w4.y *= scale; w4.z *= scale; w4.w *= scale;
    *reinterpret_cast<float4*>(out + idx) = w4;
}

extern "C" void kernel_launch(void* const* d_in, const int* in_sizes, int n_in,
                              void* d_out, int out_size, void* d_ws, size_t ws_size,
                              hipStream_t stream) {
    const float* raw_gamma = (const float*)d_in[0];
    const float* raw_lambd = (const float*)d_in[1];
    float* out = (float*)d_out;

    float* wsf       = (float*)d_ws;
    float* wsA       = wsf;            // 256 floats
    float* wsB       = wsf + NBLK;     // 256 floats
    float* blocksums = wsf + 2 * NBLK; // 256 floats

    k1_blockcomp<<<NBLK, BTH, 0, stream>>>(raw_gamma, raw_lambd, wsA, wsB);
    k3_compute<<<NBLK, BTH, 0, stream>>>(raw_gamma, raw_lambd, wsA, wsB, out, blocksums);
    k4_scale<<<N_ELEMS / (BTH * 4), BTH, 0, stream>>>(blocksums, out);
}